// Round 12
// baseline (133.371 us; speedup 1.0000x reference)
//
#include <hip/hip_runtime.h>

typedef float f32x4 __attribute__((ext_vector_type(4)));
typedef short s16x8 __attribute__((ext_vector_type(8)));

#define M_DIM 32
#define N_DIM 8192
#define K_DIM 8192
#define NBLK (K_DIM / 16)   // 512 fp4 blocks along K
#define SSTEPS 8            // 32-k steps per wave (block k-range 256)

// float -> bf16 bits, round-to-nearest-even (data has no NaNs)
__device__ inline unsigned short f2bf(float f) {
    unsigned int u = __float_as_uint(f);
    u = (u + 0x7FFFu + ((u >> 16) & 1u)) >> 16;
    return (unsigned short)u;
}

// Nearest FP4 (e2m1); ties at the boundary go DOWN (searchsorted side='left').
__device__ inline float round_fp4(float x) {
    float a = fabsf(x);
    float g;
    if (a > 2.5f)        g = (a > 5.0f) ? 6.0f : ((a > 3.5f) ? 4.0f : 3.0f);
    else if (a > 1.25f)  g = (a > 1.75f) ? 2.0f : 1.5f;
    else                 g = (a > 0.75f) ? 1.0f : ((a > 0.25f) ? 0.5f : 0.0f);
    return copysignf(g, x);
}

// Saturating RNE cast to float8_e4m3fn and back (v >= 0 here).
__device__ inline float cast_e4m3(float v) {
    v = fminf(v, 448.0f);
    if (v < 0.015625f) {                       // subnormal range, step 2^-9
        return rintf(v * 512.0f) * (1.0f / 512.0f);
    }
    int e; float m = frexpf(v, &e);            // m in [0.5, 1)
    return ldexpf(rintf(m * 16.0f) * 0.0625f, e);
}

// global_load_lds: LDS dest is WAVE-UNIFORM base; HW writes base + lane*size.
__device__ __forceinline__ void async_copy16(const void* g, void* l) {
    __builtin_amdgcn_global_load_lds((const __attribute__((address_space(1))) void*)g,
                                     (__attribute__((address_space(3))) void*)l, 16, 0, 0);
}

// ---------------------------------------------------------------------------
// Fused prep (r7 exact): blocks 0..63  -> NVFP4 fake-quant of x into xpack
//                        blocks 64..319 -> out[m][n] = bias[n]
// xpack layout: base = kstep*1024 + t*512; index lane*8+j where
//   lane = g*16 + (m&15), t = m>>4, g = k-group; holds x_dq[m][kstep*32+g*8+j]
// ---------------------------------------------------------------------------
__global__ void prep_kernel(const float* __restrict__ x,
                            const float* __restrict__ input_scale,
                            const float* __restrict__ bias,
                            unsigned short* __restrict__ xpack,
                            float* __restrict__ out) {
    if (blockIdx.x >= 64) {
        int i = (blockIdx.x - 64) * blockDim.x + threadIdx.x;  // 65536 thr * 4 f
        f32x4 b = *(const f32x4*)(bias + ((i * 4) & (N_DIM - 1)));
        *(f32x4*)(out + (size_t)i * 4) = b;
        return;
    }
    int tid = blockIdx.x * blockDim.x + threadIdx.x;   // 16384 threads
    int m = tid >> 9;          // row 0..31
    int b = tid & 511;         // 16-block along K
    const float is = input_scale[0];

    const float* xp = x + (size_t)m * K_DIM + b * 16;
    f32x4 l0 = *(const f32x4*)(xp);
    f32x4 l1 = *(const f32x4*)(xp + 4);
    f32x4 l2 = *(const f32x4*)(xp + 8);
    f32x4 l3 = *(const f32x4*)(xp + 12);
    float v[16];
    #pragma unroll
    for (int i = 0; i < 4; ++i) { v[i]=l0[i]; v[4+i]=l1[i]; v[8+i]=l2[i]; v[12+i]=l3[i]; }

    float amax = 0.f;
    #pragma unroll
    for (int i = 0; i < 16; ++i) amax = fmaxf(amax, fabsf(v[i]));

    float sf = cast_e4m3(amax / 6.0f / is);
    float scale = sf * is;

    int kstep = b >> 1;
    int t = m >> 4;
    int mrow = m & 15;
    unsigned short* base = xpack + (size_t)kstep * 1024 + t * 512;
    #pragma unroll
    for (int i = 0; i < 16; ++i) {
        float q = 0.f;
        if (scale > 0.f) q = round_fp4(v[i] / scale) * scale;
        int g = ((b & 1) << 1) + (i >> 3);   // k-group 0..3 within kstep
        int lane = g * 16 + mrow;
        int j = i & 7;
        base[lane * 8 + j] = f2bf(q);
    }
}

// ---------------------------------------------------------------------------
// Phase 2: split-K GEMM with a PURE-W global stream in the hot loop.
// Block = 64 rows x 256 k; 4 waves split rows (16 each, r7 wave structure).
// xpack slice (16 KB) + scales (4 KB) staged to LDS ONCE at block start ->
// inner loop: 2 global W loads + 2 ds_read_b128 + 1 LDS scale + 2 MFMA.
// LDS uses lgkmcnt (separate from vmcnt) -> B-reads never wait behind W.
// Grid = 128 row-tiles x 32 ksplits = 4096 blocks, LDS 20480 B exactly ->
// 8 blocks/CU, 32 waves/CU. XCD swizzle: xcd = bid&7 owns 1024 rows.
// No cross-wave reduce: waves own disjoint rows, atomicAdd directly.
// ---------------------------------------------------------------------------
__global__ __launch_bounds__(256, 8) void gemm_kernel(
    const float* __restrict__ W,
    const float* __restrict__ wscale,
    const float* __restrict__ ws2p,
    const unsigned short* __restrict__ xpack,
    float* __restrict__ out)
{
    __shared__ __align__(16) unsigned char xq[16384];  // xpack slice
    __shared__ float sc_lds[1024];                     // [64 rows][16 kblks]

    // ---- XCD-bijective swizzle (4096 = 8 XCDs x 512 blocks) ----
    const int bid   = blockIdx.x;
    const int xcd   = bid & 7;
    const int local = bid >> 3;                 // 0..511 within XCD
    const int ntile = xcd * 16 + (local >> 5);  // 0..127 (64 rows each)
    const int kb    = local & 31;               // 0..31

    const int wave = threadIdx.x >> 6;   // row sub-tile within block
    const int lane = threadIdx.x & 63;
    const int lrow = lane & 15;          // A row (n) sub-index / B m col
    const int lgrp = lane >> 4;          // k-group 0..3
    const int n0 = ntile * 64;
    const float ws2 = ws2p[0];

    // ---- stage xpack slice: ksteps [kb*8, kb*8+8) = 16 KB, linear copy ----
    {
        const unsigned short* xsrc = xpack + (size_t)kb * 8192;
        #pragma unroll
        for (int i = 0; i < 4; ++i) {
            int c = i * 4 + wave;                       // 1KB chunk, wave-uniform
            async_copy16(xsrc + c * 512 + lane * 8, xq + c * 1024);
        }
    }
    // ---- stage scales * ws2: 64 rows x 16 kblks ----
    {
        int t = threadIdx.x;
        int row = t >> 2;                // 0..63
        int c0 = (t & 3) * 4;            // 0,4,8,12
        f32x4 s4 = *(const f32x4*)(wscale + (size_t)(n0 + row) * NBLK + kb * 16 + c0);
        #pragma unroll
        for (int j = 0; j < 4; ++j) s4[j] *= ws2;
        *(f32x4*)(sc_lds + row * 16 + c0) = s4;
    }
    __syncthreads();   // drains global_load_lds (compiler emits vmcnt(0))

    // ---- per-wave sources ----
    const float* wcur = W + (size_t)(n0 + wave * 16 + lrow) * K_DIM + kb * 256 + lgrp * 8;
    const float* scur = sc_lds + (wave * 16 + lrow) * 16 + (lgrp >> 1);

    f32x4 acc0 = {0,0,0,0}, acc1 = {0,0,0,0};

    // depth-2 manual prefetch on the W stream (the ONLY global stream here)
    f32x4 a0 = *(const f32x4*)(wcur);
    f32x4 a1 = *(const f32x4*)(wcur + 4);

    #pragma unroll
    for (int s = 0; s < SSTEPS; ++s) {
        f32x4 na0, na1;
        if (s + 1 < SSTEPS) {            // static with full unroll
            na0 = *(const f32x4*)(wcur + 32);
            na1 = *(const f32x4*)(wcur + 36);
        }
        s16x8 b0 = *(const s16x8*)(xq + s * 2048 + lane * 16);
        s16x8 b1 = *(const s16x8*)(xq + s * 2048 + 1024 + lane * 16);
        float sc = scur[2 * s];
        s16x8 af;
        #pragma unroll
        for (int j = 0; j < 4; ++j) {
            af[j]     = (short)f2bf(a0[j] * sc);
            af[4 + j] = (short)f2bf(a1[j] * sc);
        }
        acc0 = __builtin_amdgcn_mfma_f32_16x16x32_bf16(af, b0, acc0, 0, 0, 0);
        acc1 = __builtin_amdgcn_mfma_f32_16x16x32_bf16(af, b1, acc1, 0, 0, 0);
        a0 = na0; a1 = na1;
        wcur += 32;
    }

    // ---- epilogue: waves own disjoint rows -> direct atomicAdd, no barrier ----
    // C/D map (verified): col = lane&15 (m sub), row = lgrp*4 + r (n sub)
    #pragma unroll
    for (int r = 0; r < 4; ++r) {
        int n = n0 + wave * 16 + lgrp * 4 + r;
        atomicAdd(out + (size_t)lrow * N_DIM + n,        acc0[r]);
        atomicAdd(out + (size_t)(16 + lrow) * N_DIM + n, acc1[r]);
    }
}

extern "C" void kernel_launch(void* const* d_in, const int* in_sizes, int n_in,
                              void* d_out, int out_size, void* d_ws, size_t ws_size,
                              hipStream_t stream) {
    const float* x           = (const float*)d_in[0];
    const float* weight_fp4  = (const float*)d_in[1];
    const float* bias        = (const float*)d_in[2];
    const float* input_scale = (const float*)d_in[3];
    const float* wscale      = (const float*)d_in[4];
    const float* ws2         = (const float*)d_in[5];
    float* out = (float*)d_out;
    unsigned short* xpack = (unsigned short*)d_ws;   // 512 KB

    prep_kernel<<<320, 256, 0, stream>>>(x, input_scale, bias, xpack, out);
    gemm_kernel<<<4096, 256, 0, stream>>>(weight_fp4, wscale, ws2, xpack, out);
}

// Round 13
// 66.953 us; speedup vs baseline: 1.9920x; 1.9920x over previous
//
#include <hip/hip_runtime.h>

typedef float f32x4 __attribute__((ext_vector_type(4)));
typedef short s16x8 __attribute__((ext_vector_type(8)));

#define M_DIM 32
#define N_DIM 8192
#define K_DIM 8192
#define NBLK (K_DIM / 16)   // 512 fp4 blocks along K
#define KSPLIT 4
#define WSTEPS 16           // MFMA k-steps per wave (512 k / 32)
#define SCL_LD 129          // padded LDS stride for scales

// float -> bf16 bits, round-to-nearest-even (data has no NaNs)
__device__ inline unsigned short f2bf(float f) {
    unsigned int u = __float_as_uint(f);
    u = (u + 0x7FFFu + ((u >> 16) & 1u)) >> 16;
    return (unsigned short)u;
}

// Nearest FP4 (e2m1); ties at the boundary go DOWN (searchsorted side='left').
__device__ inline float round_fp4(float x) {
    float a = fabsf(x);
    float g;
    if (a > 2.5f)        g = (a > 5.0f) ? 6.0f : ((a > 3.5f) ? 4.0f : 3.0f);
    else if (a > 1.25f)  g = (a > 1.75f) ? 2.0f : 1.5f;
    else                 g = (a > 0.75f) ? 1.0f : ((a > 0.25f) ? 0.5f : 0.0f);
    return copysignf(g, x);
}

// Saturating RNE cast to float8_e4m3fn and back (v >= 0 here).
__device__ inline float cast_e4m3(float v) {
    v = fminf(v, 448.0f);
    if (v < 0.015625f) {                       // subnormal range, step 2^-9
        return rintf(v * 512.0f) * (1.0f / 512.0f);
    }
    int e; float m = frexpf(v, &e);            // m in [0.5, 1)
    return ldexpf(rintf(m * 16.0f) * 0.0625f, e);
}

// ---------------------------------------------------------------------------
// Fused prep: blocks 0..63  -> NVFP4 fake-quant of x into xpack (B-frag layout)
//             blocks 64..319 -> out[m][n] = bias[n]
// ---------------------------------------------------------------------------
__global__ void prep_kernel(const float* __restrict__ x,
                            const float* __restrict__ input_scale,
                            const float* __restrict__ bias,
                            unsigned short* __restrict__ xpack,
                            float* __restrict__ out) {
    if (blockIdx.x >= 64) {
        int i = (blockIdx.x - 64) * blockDim.x + threadIdx.x;  // 65536 thr * 4 f
        f32x4 b = *(const f32x4*)(bias + ((i * 4) & (N_DIM - 1)));
        *(f32x4*)(out + (size_t)i * 4) = b;
        return;
    }
    int tid = blockIdx.x * blockDim.x + threadIdx.x;   // 16384 threads
    int m = tid >> 9;          // row 0..31
    int b = tid & 511;         // 16-block along K
    const float is = input_scale[0];

    const float* xp = x + (size_t)m * K_DIM + b * 16;
    f32x4 l0 = *(const f32x4*)(xp);
    f32x4 l1 = *(const f32x4*)(xp + 4);
    f32x4 l2 = *(const f32x4*)(xp + 8);
    f32x4 l3 = *(const f32x4*)(xp + 12);
    float v[16];
    #pragma unroll
    for (int i = 0; i < 4; ++i) { v[i]=l0[i]; v[4+i]=l1[i]; v[8+i]=l2[i]; v[12+i]=l3[i]; }

    float amax = 0.f;
    #pragma unroll
    for (int i = 0; i < 16; ++i) amax = fmaxf(amax, fabsf(v[i]));

    float sf = cast_e4m3(amax / 6.0f / is);
    float scale = sf * is;

    int kstep = b >> 1;
    int t = m >> 4;
    int mrow = m & 15;
    unsigned short* base = xpack + (size_t)kstep * 1024 + t * 512;
    #pragma unroll
    for (int i = 0; i < 16; ++i) {
        float q = 0.f;
        if (scale > 0.f) q = round_fp4(v[i] / scale) * scale;
        int g = ((b & 1) << 1) + (i >> 3);   // k-group 0..3 within kstep
        int lane = g * 16 + mrow;
        int j = i & 7;
        base[lane * 8 + j] = f2bf(q);
    }
}

// ---------------------------------------------------------------------------
// Phase 2: streaming split-K GEMM (best-known r7 structure).
// 1-D grid 2048, 256 thr (4 waves) -> 8 blocks/CU, 32 waves/CU.
// XCD-bijective swizzle: xcd = bid&7 owns a contiguous 32MB W band.
// Each wave: 16 rows x 512 k, depth-2 VGPR pipeline, scales preloaded to LDS,
// intra-block LDS reduce over 4 k-split waves, atomicAdd epilogue onto
// bias-initialized out.
// ---------------------------------------------------------------------------
__global__ __launch_bounds__(256, 8) void gemm_kernel(
    const float* __restrict__ W,
    const float* __restrict__ wscale,
    const float* __restrict__ ws2p,
    const unsigned short* __restrict__ xpack,
    float* __restrict__ out)
{
    __shared__ float shm[16 * SCL_LD];   // 8256 B; scales, then reduce buffer

    // ---- XCD-bijective swizzle (2048 = 8 XCDs x 256 blocks) ----
    const int bid   = blockIdx.x;
    const int xcd   = bid & 7;
    const int local = bid >> 3;                 // 0..255 within XCD
    const int ntile = xcd * 64 + (local >> 2);  // 0..511
    const int kb    = local & 3;                // 0..3

    const int wave = threadIdx.x >> 6;   // 0..3 : k sub-split within block
    const int lane = threadIdx.x & 63;
    const int lrow = lane & 15;          // W row (n) sub-index
    const int lgrp = lane >> 4;          // k-group 0..3
    const int n0 = ntile * 16;
    const float ws2 = ws2p[0];

    // ---- preload scales * ws2: rows n0..n0+15, scale-cols kb*128..+128 ----
    {
        int t = threadIdx.x;
        int row = t >> 4;
        int c0 = (t & 15) * 8;
        const float* s = wscale + (size_t)(n0 + row) * NBLK + kb * 128 + c0;
        #pragma unroll
        for (int j = 0; j < 8; ++j)
            shm[row * SCL_LD + c0 + j] = s[j] * ws2;
    }
    __syncthreads();

    const int kofs = kb * 2048 + wave * 512;          // this wave's k start
    const float* wcur = W + (size_t)(n0 + lrow) * K_DIM + kofs + lgrp * 8;
    const unsigned short* xcur = xpack + (size_t)(kofs >> 5) * 1024 + lane * 8;
    const float* sbase = shm + lrow * SCL_LD + wave * 32 + (lgrp >> 1);

    f32x4 acc0 = {0,0,0,0}, acc1 = {0,0,0,0};

    // depth-2 software pipeline (compiler inserts the vmcnt waits)
    f32x4 a0 = *(const f32x4*)(wcur);
    f32x4 a1 = *(const f32x4*)(wcur + 4);
    s16x8 b0 = *(const s16x8*)(xcur);
    s16x8 b1 = *(const s16x8*)(xcur + 512);

    #pragma unroll
    for (int s = 0; s < WSTEPS; ++s) {
        f32x4 na0, na1; s16x8 nb0, nb1;
        if (s + 1 < WSTEPS) {             // static with full unroll
            na0 = *(const f32x4*)(wcur + 32);
            na1 = *(const f32x4*)(wcur + 36);
            nb0 = *(const s16x8*)(xcur + 1024);
            nb1 = *(const s16x8*)(xcur + 1536);
        }
        float sc = sbase[s * 2];
        s16x8 af;
        #pragma unroll
        for (int j = 0; j < 4; ++j) {
            af[j]     = (short)f2bf(a0[j] * sc);
            af[4 + j] = (short)f2bf(a1[j] * sc);
        }
        acc0 = __builtin_amdgcn_mfma_f32_16x16x32_bf16(af, b0, acc0, 0, 0, 0);
        acc1 = __builtin_amdgcn_mfma_f32_16x16x32_bf16(af, b1, acc1, 0, 0, 0);
        a0 = na0; a1 = na1; b0 = nb0; b1 = nb1;
        wcur += 32;
        xcur += 1024;
    }

    // ---- intra-block reduce over the 4 k-split waves ----
    __syncthreads();                      // scale reads done; reuse shm
    float* red = shm;                     // [4][512]
    #pragma unroll
    for (int r = 0; r < 4; ++r) {
        red[wave * 512 + lane * 8 + r]     = acc0[r];
        red[wave * 512 + lane * 8 + 4 + r] = acc1[r];
    }
    __syncthreads();

    // 256 threads -> 512 outputs; D layout: col(lane&15)=m, row((lane>>4)*4+r)=n
    #pragma unroll
    for (int h = 0; h < 2; ++h) {
        int j = threadIdx.x + h * 256;
        float v = red[j] + red[512 + j] + red[1024 + j] + red[1536 + j];
        int l = j >> 3, t = (j >> 2) & 1, r = j & 3;
        int m = t * 16 + (l & 15);
        int n = n0 + ((l >> 4) << 2) + r;
        atomicAdd(out + (size_t)m * N_DIM + n, v);
    }
}

extern "C" void kernel_launch(void* const* d_in, const int* in_sizes, int n_in,
                              void* d_out, int out_size, void* d_ws, size_t ws_size,
                              hipStream_t stream) {
    const float* x           = (const float*)d_in[0];
    const float* weight_fp4  = (const float*)d_in[1];
    const float* bias        = (const float*)d_in[2];
    const float* input_scale = (const float*)d_in[3];
    const float* wscale      = (const float*)d_in[4];
    const float* ws2         = (const float*)d_in[5];
    float* out = (float*)d_out;
    unsigned short* xpack = (unsigned short*)d_ws;   // 512 KB

    prep_kernel<<<320, 256, 0, stream>>>(x, input_scale, bias, xpack, out);
    gemm_kernel<<<2048, 256, 0, stream>>>(weight_fp4, wscale, ws2, xpack, out);
}